// Round 12
// baseline (530.238 us; speedup 1.0000x reference)
//
#include <hip/hip_runtime.h>
#include <cstddef>
#include <cstdint>

#define Hdim 1024
#define Bdim 64
#define Idim 128

// BETA = 10.0 / 0.192
#define BETA_F 52.083333333333336f
#define INV_BETA_F 0.0192f
#define LN2_F 0.6931471805599453f

__device__ __forceinline__ float sigf(float x) {
    return 1.0f / (1.0f + __expf(-x));
}

// log(cosh(t)) = |t| + log1p(exp(-2|t|)) - ln2   (stable, matches fp32 ref)
__device__ __forceinline__ float logcoshf_(float t) {
    float a = fabsf(t);
    return a + log1pf(__expf(-2.0f * a)) - LN2_F;
}

// Fire-and-forget 16B/lane HBM->LDS DMA with NT cache policy (aux=2 -> `nt`
// bit): no destination VGPRs (MLP at zero register cost) AND no LLC
// allocation (round 10 proved the LLC dirty-writeback drag was the 163-µs
// cap; nt on register loads gave 163->~140). This combines both fixes:
// sustained 8 KiB/wave in flight + clean NT stream.
__device__ __forceinline__ void stage16nt(const float* gsrc, float* ldst) {
    auto g = (const __attribute__((address_space(1))) uint32_t*)(uintptr_t)gsrc;
    auto l = (__attribute__((address_space(3))) uint32_t*)(uint32_t)(uintptr_t)ldst;
    __builtin_amdgcn_global_load_lds(g, l, 16, 0, 2 /* NT */);
}

// ---------------------------------------------------------------------------
// Pre-kernel: rates r = sigmoid(v_t), membx = p_r@x + b_r, gatex = |p_r|@x+g_z
// ---------------------------------------------------------------------------
__global__ void pre_kernel(const float* __restrict__ x,
                           const float* __restrict__ v_t,
                           const float* __restrict__ p_r,
                           const float* __restrict__ b_r,
                           const float* __restrict__ g_z,
                           float* __restrict__ r_ws,
                           float* __restrict__ membx,
                           float* __restrict__ gatex) {
    const int j = blockIdx.x;   // 0..H-1
    const int b = threadIdx.x;  // 0..B-1
    const float* pr = p_r + (size_t)j * Idim;
    float accm = 0.0f, accg = 0.0f;
#pragma unroll 4
    for (int i = 0; i < Idim; ++i) {
        float p  = pr[i];              // wave-uniform -> scalar load
        float xv = x[i * Bdim + b];    // coalesced
        accm = fmaf(p, xv, accm);
        accg = fmaf(fabsf(p), xv, accg);
    }
    membx[j * Bdim + b] = accm + b_r[j];
    gatex[j * Bdim + b] = accg + g_z[j];

    int id = j * Bdim + b;  // 0..65535
    r_ws[id] = sigf(v_t[id]);
}

// ---------------------------------------------------------------------------
// Main kernel: one block per row j (grid=1024), 4 waves, 16 batches/wave.
// HBM->LDS NT-DMA double-buffer per wave (8 KiB/batch: X row + U row).
//
// Queue-order discipline (round 6/7): vmcnt retires OLDEST first, so all
// register loads the compute consumes (rj, rv, vt/gx/mx) issue BEFORE
// STAGE(n+1); their waitcnt then leaves the 8 staging DMAs outstanding.
// Staging is only drained at the NEXT iteration top, a full compute phase
// after issue.
//
// Why this config post-nt (round 11 analysis): register-load kernels are
// bursty (avg in-flight << peak) and VGPR-binned to <=16 waves/CU; the DMA
// pipeline sustains 2 blk x 4 waves x 8 KiB = 64 KB/CU in flight at VGPR=88.
// Per-CU BW floor ~43 µs vs VALU ~8 µs -> cleanly BW-bound if NT sustains.
// ---------------------------------------------------------------------------
__global__ __launch_bounds__(256, 4) void main_kernel(
    const float* __restrict__ X,
    const float* __restrict__ U,
    const float* __restrict__ raw_w_r,
    const float* __restrict__ c_x,
    const float* __restrict__ c_u,
    const float* __restrict__ c_U,
    const float* __restrict__ v_t,
    const float* __restrict__ a_exc,
    const float* __restrict__ a_inh,
    const float* __restrict__ r_ws,
    const float* __restrict__ membx,
    const float* __restrict__ gatex,
    float* __restrict__ out) {
    __shared__ __align__(16) float s_zx[Hdim];
    __shared__ __align__(16) float s_zu[Hdim];
    __shared__ __align__(16) float s_uc[Hdim];
    __shared__ __align__(16) float s_wr[Hdim];
    __shared__ __align__(16) float s_stage[4][2][2048];  // [wave][buf][X|U] 64K

    const int j   = blockIdx.x;
    const int tid = threadIdx.x;

    const float Aexc = 10.0f * sigf(a_exc[0]);
    const float Ainh = 10.0f * sigf(a_inh[0]);

    // ---- stage per-row transforms into LDS (256 thr x 4 elems) ----
    {
        const int k = tid * 4;
        const size_t ro = (size_t)j * Hdim + k;
        float4 rw = *(const float4*)(raw_w_r + ro);
        float4 cx = *(const float4*)(c_x + ro);
        float4 cu = *(const float4*)(c_u + ro);
        float4 cN = *(const float4*)(c_U + ro);

        s_wr[k + 0] = logcoshf_(BETA_F * rw.x) * INV_BETA_F;
        s_wr[k + 1] = logcoshf_(BETA_F * rw.y) * INV_BETA_F;
        s_wr[k + 2] = logcoshf_(BETA_F * rw.z) * INV_BETA_F;
        s_wr[k + 3] = logcoshf_(BETA_F * rw.w) * INV_BETA_F;

        s_zx[k + 0] = 0.001f + 0.099f * sigf(cx.x);
        s_zx[k + 1] = 0.001f + 0.099f * sigf(cx.y);
        s_zx[k + 2] = 0.001f + 0.099f * sigf(cx.z);
        s_zx[k + 3] = 0.001f + 0.099f * sigf(cx.w);

        s_zu[k + 0] = 0.001f + 0.099f * sigf(cu.x);
        s_zu[k + 1] = 0.001f + 0.099f * sigf(cu.y);
        s_zu[k + 2] = 0.001f + 0.099f * sigf(cu.z);
        s_zu[k + 3] = 0.001f + 0.099f * sigf(cu.w);

        s_uc[k + 0] = 0.9f * sigf(cN.x);
        s_uc[k + 1] = 0.9f * sigf(cN.y);
        s_uc[k + 2] = 0.9f * sigf(cN.z);
        s_uc[k + 3] = 0.9f * sigf(cN.w);
    }
    __syncthreads();

    const int wave = tid >> 6;
    const int lane = tid & 63;

    float* const st0 = &s_stage[wave][0][0];
    float* const st1 = &s_stage[wave][1][0];

    // X row -> buf[0..1023], U row -> buf[1024..2047]; 8 x 1 KiB NT-DMA
#define STAGE_BATCH(b_, buf_)                                                 \
    {                                                                         \
        const float* Xb_ = X + (size_t)(b_) * (Hdim * Hdim) + (size_t)j * Hdim;\
        const float* Ub_ = U + (size_t)(b_) * (Hdim * Hdim) + (size_t)j * Hdim;\
        _Pragma("unroll")                                                     \
        for (int c_ = 0; c_ < 4; ++c_) {                                      \
            stage16nt(Xb_ + c_ * 256 + lane * 4, (buf_) + c_ * 256);          \
            stage16nt(Ub_ + c_ * 256 + lane * 4, (buf_) + 1024 + c_ * 256);   \
        }                                                                     \
    }

    // prologue: stage first batch (latency exposed once per wave)
    STAGE_BATCH(wave, st0)

    for (int n = 0; n < 16; ++n) {
        const int b = wave + n * 4;
        float* cur = (n & 1) ? st1 : st0;
        float* nxt = (n & 1) ? st0 : st1;

        // batch n's staging was issued one full compute phase ago
        asm volatile("s_waitcnt vmcnt(0)" ::: "memory");
        __builtin_amdgcn_sched_barrier(0);

        // ---- EARLY load group: everything compute consumes, issued BEFORE
        // the next-batch staging so no use of it drains the staging queue.
        const float* rb = r_ws + b * Hdim;
        const float rj = rb[j];
        const float4 rv0 = *(const float4*)(rb + 0 * 256 + lane * 4);
        const float4 rv1 = *(const float4*)(rb + 1 * 256 + lane * 4);
        const float4 rv2 = *(const float4*)(rb + 2 * 256 + lane * 4);
        const float4 rv3 = *(const float4*)(rb + 3 * 256 + lane * 4);
        const float vt = v_t[(size_t)b * Hdim + j];
        const float gx = gatex[j * Bdim + b];
        const float mx = membx[j * Bdim + b];
        __builtin_amdgcn_sched_barrier(0);

        // fire-and-forget: stream batch n+1 while we compute batch n
        if (n < 15) STAGE_BATCH(b + 4, nxt)
        __builtin_amdgcn_sched_barrier(0);

        float rec = 0.0f, gate = 0.0f;
#define ITBLOCK(it, rvv)                                                      \
    {                                                                         \
        const float Ah = ((it) < 2) ? Aexc : Ainh;  /* k<512 : k>=512 */      \
        const int k = (it) * 256 + lane * 4;                                  \
        float4 Xv = *(const float4*)(cur + k);                                \
        float4 Uv = *(const float4*)(cur + 1024 + k);                         \
        float4 zx = *(const float4*)(s_zx + k);                               \
        float4 zu = *(const float4*)(s_zu + k);                               \
        float4 uc = *(const float4*)(s_uc + k);                               \
        float4 wr = *(const float4*)(s_wr + k);                               \
        COMPONENT(x, rvv)                                                     \
        COMPONENT(y, rvv)                                                     \
        COMPONENT(z, rvv)                                                     \
        COMPONENT(w, rvv)                                                     \
    }
#define COMPONENT(c, rvv)                                                     \
    {                                                                         \
        float xn = zx.c + (1.0f - zx.c) * Xv.c - Uv.c * Xv.c * rj;            \
        float un = uc.c * zu.c + (1.0f - zu.c) * Uv.c +                       \
                   uc.c * (1.0f - Uv.c) * rj;                                 \
        un = fminf(fmaxf(un, uc.c), 1.0f);                                    \
        rec  = fmaf(xn * un * wr.c, rvv.c, rec);                              \
        gate = fmaf(wr.c * Ah, rvv.c, gate);                                  \
    }
        ITBLOCK(0, rv0)
        ITBLOCK(1, rv1)
        ITBLOCK(2, rv2)
        ITBLOCK(3, rv3)
#undef COMPONENT
#undef ITBLOCK

        // butterfly reduce across the 64-lane wave
#pragma unroll
        for (int off = 32; off > 0; off >>= 1) {
            rec  += __shfl_xor(rec, off, 64);
            gate += __shfl_xor(gate, off, 64);
        }

        if (lane == 0) {
            float z  = 0.1f * sigf(gate + gx);
            float vn = (1.0f - z) * vt + 0.1f * (rec + mx);
            out[(size_t)b * Hdim + j] = vn;
        }
    }
#undef STAGE_BATCH
}

extern "C" void kernel_launch(void* const* d_in, const int* in_sizes, int n_in,
                              void* d_out, int out_size, void* d_ws, size_t ws_size,
                              hipStream_t stream) {
    const float* x       = (const float*)d_in[0];   // (I,B)
    const float* v_t     = (const float*)d_in[1];   // (B,H)
    const float* X       = (const float*)d_in[2];   // (B,H,H)
    const float* U       = (const float*)d_in[3];   // (B,H,H)
    const float* raw_w_r = (const float*)d_in[4];   // (H,H)
    const float* p_r     = (const float*)d_in[5];   // (H,I)
    const float* b_r     = (const float*)d_in[6];   // (H,1)
    const float* g_z     = (const float*)d_in[7];   // (H,1)
    const float* c_x     = (const float*)d_in[8];   // (H,H)
    const float* c_u     = (const float*)d_in[9];   // (H,H)
    const float* c_U     = (const float*)d_in[10];  // (H,H)
    const float* a_exc   = (const float*)d_in[11];  // scalar
    const float* a_inh   = (const float*)d_in[12];  // scalar

    float* out = (float*)d_out;  // (B,H) fp32

    float* r_ws  = (float*)d_ws;              // B*H
    float* membx = r_ws + Bdim * Hdim;        // H*B
    float* gatex = membx + Hdim * Bdim;       // H*B

    pre_kernel<<<dim3(Hdim), dim3(Bdim), 0, stream>>>(
        x, v_t, p_r, b_r, g_z, r_ws, membx, gatex);

    main_kernel<<<dim3(Hdim), dim3(256), 0, stream>>>(
        X, U, raw_w_r, c_x, c_u, c_U, v_t, a_exc, a_inh,
        r_ws, membx, gatex, out);
}

// Round 13
// 523.693 us; speedup vs baseline: 1.0125x; 1.0125x over previous
//
#include <hip/hip_runtime.h>
#include <cstddef>
#include <cstdint>

#define Hdim 1024
#define Bdim 64
#define Idim 128

// BETA = 10.0 / 0.192
#define BETA_F 52.083333333333336f
#define INV_BETA_F 0.0192f
#define LN2_F 0.6931471805599453f

// clang native vector type — __builtin_nontemporal_load requires a pointer
// to scalar/native-vector, NOT HIP_vector_type (round-9 compile error).
typedef float floatx4 __attribute__((ext_vector_type(4)));

__device__ __forceinline__ float sigf(float x) {
    return 1.0f / (1.0f + __expf(-x));
}

// log(cosh(t)) = |t| + log1p(exp(-2|t|)) - ln2   (stable, matches fp32 ref)
__device__ __forceinline__ float logcoshf_(float t) {
    float a = fabsf(t);
    return a + log1pf(__expf(-2.0f * a)) - LN2_F;
}

// Non-temporal float4 load (`nt` bit): X/U are read exactly once; nt skips
// LLC allocation -> no dirty-line evictions/writebacks behind the stream.
// Round 10 verified: main_kernel 163 -> ~146 µs from this alone. The one
// real lever of the session; every concurrency/pipelining axis was null.
__device__ __forceinline__ floatx4 ldnt4(const float* p) {
    return __builtin_nontemporal_load((const floatx4*)p);
}

// ---------------------------------------------------------------------------
// Pre-kernel: rates r = sigmoid(v_t), membx = p_r@x + b_r, gatex = |p_r|@x+g_z
// ---------------------------------------------------------------------------
__global__ void pre_kernel(const float* __restrict__ x,
                           const float* __restrict__ v_t,
                           const float* __restrict__ p_r,
                           const float* __restrict__ b_r,
                           const float* __restrict__ g_z,
                           float* __restrict__ r_ws,
                           float* __restrict__ membx,
                           float* __restrict__ gatex) {
    const int j = blockIdx.x;   // 0..H-1
    const int b = threadIdx.x;  // 0..B-1
    const float* pr = p_r + (size_t)j * Idim;
    float accm = 0.0f, accg = 0.0f;
#pragma unroll 4
    for (int i = 0; i < Idim; ++i) {
        float p  = pr[i];              // wave-uniform -> scalar load
        float xv = x[i * Bdim + b];    // coalesced
        accm = fmaf(p, xv, accm);
        accg = fmaf(fabsf(p), xv, accg);
    }
    membx[j * Bdim + b] = accm + b_r[j];
    gatex[j * Bdim + b] = accg + g_z[j];

    int id = j * Bdim + b;  // 0..65535
    r_ws[id] = sigf(v_t[id]);
}

// ---------------------------------------------------------------------------
// Main kernel (FINAL, round-11 best = 526.0 µs e2e, main ~140 µs):
// grid = 1024 blocks = (row-pair, batch-half); rows j0,j0+1 for 32 batches;
// 4 waves x 8 batches. NT X/U register loads; rv loaded once, reused by
// both rows; 16 waves/CU (VGPR<=64 bin).
//
// Session roofline evidence: post-NT time is invariant (140-146 µs) across
// waves 8/16, VGPR-burst vs sustained LDS-DMA staging, explicit vmcnt
// queue-ordering, and -17% demand traffic. Sustained read = 537 MB/140 µs
// = 3.84 TB/s — above the m13 copy's read-side rate (3.15); fill writes at
// 6.7 (writes need no miss tracking). The cap is the per-CU read-miss
// concurrency x HBM latency product, not anything schedulable in software.
// ---------------------------------------------------------------------------
__global__ __launch_bounds__(256, 4) void main_kernel(
    const float* __restrict__ X,
    const float* __restrict__ U,
    const float* __restrict__ raw_w_r,
    const float* __restrict__ c_x,
    const float* __restrict__ c_u,
    const float* __restrict__ c_U,
    const float* __restrict__ v_t,
    const float* __restrict__ a_exc,
    const float* __restrict__ a_inh,
    const float* __restrict__ r_ws,
    const float* __restrict__ membx,
    const float* __restrict__ gatex,
    float* __restrict__ out) {
    __shared__ __align__(16) float s_zx[2][Hdim];
    __shared__ __align__(16) float s_zu[2][Hdim];
    __shared__ __align__(16) float s_uc[2][Hdim];
    __shared__ __align__(16) float s_wr[2][Hdim];

    const int j0    = (blockIdx.x >> 1) * 2;            // row pair
    const int bbase = (blockIdx.x & 1) * (Bdim / 2);    // batch half
    const int tid   = threadIdx.x;

    const float Aexc = 10.0f * sigf(a_exc[0]);
    const float Ainh = 10.0f * sigf(a_inh[0]);

    // ---- stage per-row transforms for BOTH rows (512 float4s per array) ----
#pragma unroll
    for (int f = tid; f < 512; f += 256) {
        const int row = f >> 8;          // 0 or 1
        const int k   = (f & 255) * 4;   // 0..1020
        const size_t ro = (size_t)(j0 + row) * Hdim + k;
        float4 rw = *(const float4*)(raw_w_r + ro);
        float4 cx = *(const float4*)(c_x + ro);
        float4 cu = *(const float4*)(c_u + ro);
        float4 cN = *(const float4*)(c_U + ro);

        s_wr[row][k + 0] = logcoshf_(BETA_F * rw.x) * INV_BETA_F;
        s_wr[row][k + 1] = logcoshf_(BETA_F * rw.y) * INV_BETA_F;
        s_wr[row][k + 2] = logcoshf_(BETA_F * rw.z) * INV_BETA_F;
        s_wr[row][k + 3] = logcoshf_(BETA_F * rw.w) * INV_BETA_F;

        s_zx[row][k + 0] = 0.001f + 0.099f * sigf(cx.x);
        s_zx[row][k + 1] = 0.001f + 0.099f * sigf(cx.y);
        s_zx[row][k + 2] = 0.001f + 0.099f * sigf(cx.z);
        s_zx[row][k + 3] = 0.001f + 0.099f * sigf(cx.w);

        s_zu[row][k + 0] = 0.001f + 0.099f * sigf(cu.x);
        s_zu[row][k + 1] = 0.001f + 0.099f * sigf(cu.y);
        s_zu[row][k + 2] = 0.001f + 0.099f * sigf(cu.z);
        s_zu[row][k + 3] = 0.001f + 0.099f * sigf(cu.w);

        s_uc[row][k + 0] = 0.9f * sigf(cN.x);
        s_uc[row][k + 1] = 0.9f * sigf(cN.y);
        s_uc[row][k + 2] = 0.9f * sigf(cN.z);
        s_uc[row][k + 3] = 0.9f * sigf(cN.w);
    }
    __syncthreads();

    const int wave = tid >> 6;
    const int lane = tid & 63;

    for (int bo = wave; bo < Bdim / 2; bo += 4) {
        const int b = bbase + bo;
        const float* Xb = X + (size_t)b * Hdim * Hdim + (size_t)j0 * Hdim;
        const float* Ub = U + (size_t)b * Hdim * Hdim + (size_t)j0 * Hdim;
        const float* rb = r_ws + b * Hdim;
        const float rj0 = rb[j0];      // r[j0,b]
        const float rj1 = rb[j0 + 1];  // r[j1,b]

        float rec0 = 0.0f, gate0 = 0.0f;
        float rec1 = 0.0f, gate1 = 0.0f;
#pragma unroll 2
        for (int it = 0; it < 4; ++it) {
            const float Ah = (it < 2) ? Aexc : Ainh;  // k<512 : k>=512
            const int k = it * 256 + lane * 4;
            float4 rv   = *(const float4*)(rb + k);  // cached (L2-resident)
            floatx4 Xv0 = ldnt4(Xb + k);             // nt: stream, no LLC alloc
            floatx4 Xv1 = ldnt4(Xb + Hdim + k);
            floatx4 Uv0 = ldnt4(Ub + k);
            floatx4 Uv1 = ldnt4(Ub + Hdim + k);
            float4 zx0 = *(const float4*)(&s_zx[0][k]);
            float4 zx1 = *(const float4*)(&s_zx[1][k]);
            float4 zu0 = *(const float4*)(&s_zu[0][k]);
            float4 zu1 = *(const float4*)(&s_zu[1][k]);
            float4 uc0 = *(const float4*)(&s_uc[0][k]);
            float4 uc1 = *(const float4*)(&s_uc[1][k]);
            float4 wr0 = *(const float4*)(&s_wr[0][k]);
            float4 wr1 = *(const float4*)(&s_wr[1][k]);

// ext_vector uses [i]; float4 uses .x/.y/.z/.w — map via component index
#define COMPONENT(ci, c, Xv, Uv, zx, zu, uc, wr, rj, rec, gate)               \
    {                                                                         \
        float Xs = Xv[ci], Us = Uv[ci];                                       \
        float xn = zx.c + (1.0f - zx.c) * Xs - Us * Xs * rj;                  \
        float un = uc.c * zu.c + (1.0f - zu.c) * Us +                         \
                   uc.c * (1.0f - Us) * rj;                                   \
        un = fminf(fmaxf(un, uc.c), 1.0f);                                    \
        rec  = fmaf(xn * un * wr.c, rv.c, rec);                               \
        gate = fmaf(wr.c * Ah, rv.c, gate);                                   \
    }
            COMPONENT(0, x, Xv0, Uv0, zx0, zu0, uc0, wr0, rj0, rec0, gate0)
            COMPONENT(1, y, Xv0, Uv0, zx0, zu0, uc0, wr0, rj0, rec0, gate0)
            COMPONENT(2, z, Xv0, Uv0, zx0, zu0, uc0, wr0, rj0, rec0, gate0)
            COMPONENT(3, w, Xv0, Uv0, zx0, zu0, uc0, wr0, rj0, rec0, gate0)
            COMPONENT(0, x, Xv1, Uv1, zx1, zu1, uc1, wr1, rj1, rec1, gate1)
            COMPONENT(1, y, Xv1, Uv1, zx1, zu1, uc1, wr1, rj1, rec1, gate1)
            COMPONENT(2, z, Xv1, Uv1, zx1, zu1, uc1, wr1, rj1, rec1, gate1)
            COMPONENT(3, w, Xv1, Uv1, zx1, zu1, uc1, wr1, rj1, rec1, gate1)
#undef COMPONENT
        }

        // uniform tail loads before the reduce (L2-resident)
        const float vt0 = v_t[(size_t)b * Hdim + j0];
        const float vt1 = v_t[(size_t)b * Hdim + j0 + 1];
        const float gx0 = gatex[j0 * Bdim + b];
        const float gx1 = gatex[(j0 + 1) * Bdim + b];
        const float mx0 = membx[j0 * Bdim + b];
        const float mx1 = membx[(j0 + 1) * Bdim + b];

        // butterfly reduce across the 64-lane wave
#pragma unroll
        for (int off = 32; off > 0; off >>= 1) {
            rec0  += __shfl_xor(rec0, off, 64);
            gate0 += __shfl_xor(gate0, off, 64);
            rec1  += __shfl_xor(rec1, off, 64);
            gate1 += __shfl_xor(gate1, off, 64);
        }

        if (lane == 0) {
            float z0 = 0.1f * sigf(gate0 + gx0);
            out[(size_t)b * Hdim + j0] =
                (1.0f - z0) * vt0 + 0.1f * (rec0 + mx0);
            float z1 = 0.1f * sigf(gate1 + gx1);
            out[(size_t)b * Hdim + j0 + 1] =
                (1.0f - z1) * vt1 + 0.1f * (rec1 + mx1);
        }
    }
}

extern "C" void kernel_launch(void* const* d_in, const int* in_sizes, int n_in,
                              void* d_out, int out_size, void* d_ws, size_t ws_size,
                              hipStream_t stream) {
    const float* x       = (const float*)d_in[0];   // (I,B)
    const float* v_t     = (const float*)d_in[1];   // (B,H)
    const float* X       = (const float*)d_in[2];   // (B,H,H)
    const float* U       = (const float*)d_in[3];   // (B,H,H)
    const float* raw_w_r = (const float*)d_in[4];   // (H,H)
    const float* p_r     = (const float*)d_in[5];   // (H,I)
    const float* b_r     = (const float*)d_in[6];   // (H,1)
    const float* g_z     = (const float*)d_in[7];   // (H,1)
    const float* c_x     = (const float*)d_in[8];   // (H,H)
    const float* c_u     = (const float*)d_in[9];   // (H,H)
    const float* c_U     = (const float*)d_in[10];  // (H,H)
    const float* a_exc   = (const float*)d_in[11];  // scalar
    const float* a_inh   = (const float*)d_in[12];  // scalar

    float* out = (float*)d_out;  // (B,H) fp32

    float* r_ws  = (float*)d_ws;              // B*H
    float* membx = r_ws + Bdim * Hdim;        // H*B
    float* gatex = membx + Hdim * Bdim;       // H*B

    pre_kernel<<<dim3(Hdim), dim3(Bdim), 0, stream>>>(
        x, v_t, p_r, b_r, g_z, r_ws, membx, gatex);

    main_kernel<<<dim3(Hdim), dim3(256), 0, stream>>>(
        X, U, raw_w_r, c_x, c_u, c_U, v_t, a_exc, a_inh,
        r_ws, membx, gatex, out);
}